// Round 5
// baseline (339.870 us; speedup 1.0000x reference)
//
#include <hip/hip_runtime.h>

#define NH 16
#define HD 64

typedef __attribute__((ext_vector_type(8))) _Float16 f16x8;
typedef __attribute__((ext_vector_type(4))) float f32x4;
typedef __attribute__((ext_vector_type(8))) unsigned short us8;
typedef __attribute__((ext_vector_type(4))) unsigned short us4;

__device__ __forceinline__ unsigned short f2h(float f) {
    _Float16 h = (_Float16)f;
    return __builtin_bit_cast(unsigned short, h);
}

// ---------------------------------------------------------------------------
// cast fp32 -> fp16, 4 elems/thread
// ---------------------------------------------------------------------------
__global__ __launch_bounds__(256)
void cast_f16(const float* __restrict__ in, unsigned short* __restrict__ out) {
    size_t i = ((size_t)blockIdx.x * 256 + threadIdx.x) * 4;
    float4 v = *reinterpret_cast<const float4*>(in + i);
    us4 w;
    w[0] = f2h(v.x); w[1] = f2h(v.y); w[2] = f2h(v.z); w[3] = f2h(v.w);
    *reinterpret_cast<us4*>(out + i) = w;
}

// ---------------------------------------------------------------------------
// transpose + cast: in fp32 [R,C] -> out fp16 [C,R].  64x64 tiles.
// ---------------------------------------------------------------------------
__global__ __launch_bounds__(256)
void transpose_cast(const float* __restrict__ in, unsigned short* __restrict__ out,
                    int R, int C) {
    __shared__ float T[64][65];
    const int c0 = blockIdx.x * 64, r0 = blockIdx.y * 64;
    const int tid = threadIdx.x;
    const int rr = tid >> 4, cc4 = (tid & 15) * 4;
    #pragma unroll
    for (int p = 0; p < 4; ++p) {
        int r = rr + p * 16;
        float4 v = *reinterpret_cast<const float4*>(
            in + (size_t)(r0 + r) * C + c0 + cc4);
        T[r][cc4] = v.x; T[r][cc4 + 1] = v.y; T[r][cc4 + 2] = v.z; T[r][cc4 + 3] = v.w;
    }
    __syncthreads();
    #pragma unroll
    for (int p = 0; p < 4; ++p) {
        int orow = rr + p * 16;     // output row = input col
        us4 w;
        #pragma unroll
        for (int j = 0; j < 4; ++j) w[j] = f2h(T[cc4 + j][orow]);
        *reinterpret_cast<us4*>(out + (size_t)(c0 + orow) * R + r0 + cc4) = w;
    }
}

// ---------------------------------------------------------------------------
// LDS staging with XOR swizzle (rows of 128B = 64 fp16).
// lds byte = r*128 + ((slot*16) ^ ((r&7)<<4))
// ---------------------------------------------------------------------------
__device__ __forceinline__ void stage128(unsigned short* dst,
                                         const unsigned short* src, int stride) {
    const int tid = threadIdx.x;
    #pragma unroll
    for (int p = 0; p < 4; ++p) {
        int idx = tid + p * 256;
        int r = idx >> 3;
        int slot = idx & 7;
        us8 v = *reinterpret_cast<const us8*>(src + (size_t)r * stride + slot * 8);
        int cb = (slot << 4) ^ ((r & 7) << 4);
        *reinterpret_cast<us8*>(reinterpret_cast<char*>(dst) + r * 128 + cb) = v;
    }
}

// Fragment load: lane l -> row row0+(l&15), bytes [ks*64 + (l>>4)*16, +16) ^ swz
__device__ __forceinline__ f16x8 frag16(const unsigned short* base, int row0, int ks) {
    const int lane = threadIdx.x & 63;
    const int r = row0 + (lane & 15);
    int cb = ((ks << 6) + (lane & 48)) ^ ((r & 7) << 4);
    return *reinterpret_cast<const f16x8*>(
        reinterpret_cast<const char*>(base) + r * 128 + cb);
}

// ---------------------------------------------------------------------------
// K/V staging split into issue (global->reg) and write (reg->LDS, swizzled)
// ---------------------------------------------------------------------------
__device__ __forceinline__ void ldKV(us8 (&rk)[2], us8 (&rv)[2],
                                     const unsigned short* kg,
                                     const unsigned short* vg, int tid) {
    const int r0 = tid >> 3, slot = tid & 7;
    rk[0] = *reinterpret_cast<const us8*>(kg + (size_t)r0 * 64 + slot * 8);
    rk[1] = *reinterpret_cast<const us8*>(kg + (size_t)(r0 + 32) * 64 + slot * 8);
    rv[0] = *reinterpret_cast<const us8*>(vg + (size_t)r0 * 2048 + slot * 8);
    rv[1] = *reinterpret_cast<const us8*>(vg + (size_t)(r0 + 32) * 2048 + slot * 8);
}

__device__ __forceinline__ void wrKV(const us8 (&rk)[2], const us8 (&rv)[2],
                                     unsigned short* Ks, unsigned short* Vs, int tid) {
    const int r0 = tid >> 3, slot = tid & 7;
    const int cb = (slot << 4) ^ ((r0 & 7) << 4);   // (r0+32)&7 == r0&7
    *reinterpret_cast<us8*>(reinterpret_cast<char*>(Ks) + r0 * 128 + cb) = rk[0];
    *reinterpret_cast<us8*>(reinterpret_cast<char*>(Ks) + (r0 + 32) * 128 + cb) = rk[1];
    *reinterpret_cast<us8*>(reinterpret_cast<char*>(Vs) + r0 * 128 + cb) = rv[0];
    *reinterpret_cast<us8*>(reinterpret_cast<char*>(Vs) + (r0 + 32) * 128 + cb) = rv[1];
}

// ---------------------------------------------------------------------------
// MFMA GEMM core: C[M,N] = A[M,K] @ Bt[N,K]^T.  128x128 tile, BK=64, 4 waves.
// MODE 0: proj  (fp32 C + bias)
// MODE 1: qkv   (split into q,k [B,H,S,64] fp16 and v^T [B,H,64,S] fp16)
// ---------------------------------------------------------------------------
template<int MODE>
__global__ __launch_bounds__(256)
void gemm_f16(const unsigned short* __restrict__ A,
              const unsigned short* __restrict__ Bt,
              const float* __restrict__ bias,
              float* __restrict__ C,
              unsigned short* __restrict__ qb,
              unsigned short* __restrict__ kb,
              unsigned short* __restrict__ vtb,
              int M, int N, int K) {
    __shared__ __align__(16) unsigned short As[128 * 64];
    __shared__ __align__(16) unsigned short Bs[128 * 64];

    const int tid = threadIdx.x;
    const int wid = tid >> 6, lane = tid & 63, g = lane >> 4;
    const int wr = wid >> 1, wc = wid & 1;
    const int m0 = blockIdx.y * 128, n0 = blockIdx.x * 128;

    f32x4 acc[4][4];
    #pragma unroll
    for (int i = 0; i < 4; ++i)
        #pragma unroll
        for (int j = 0; j < 4; ++j) {
            acc[i][j][0] = 0.f; acc[i][j][1] = 0.f;
            acc[i][j][2] = 0.f; acc[i][j][3] = 0.f;
        }

    for (int k0 = 0; k0 < K; k0 += 64) {
        __syncthreads();
        stage128(As, A + (size_t)m0 * K + k0, K);
        stage128(Bs, Bt + (size_t)n0 * K + k0, K);
        __syncthreads();

        f16x8 af[4][2], bf[4][2];
        #pragma unroll
        for (int mi = 0; mi < 4; ++mi)
            #pragma unroll
            for (int ks = 0; ks < 2; ++ks)
                af[mi][ks] = frag16(As, wr * 64 + mi * 16, ks);
        #pragma unroll
        for (int ni = 0; ni < 4; ++ni)
            #pragma unroll
            for (int ks = 0; ks < 2; ++ks)
                bf[ni][ks] = frag16(Bs, wc * 64 + ni * 16, ks);

        __builtin_amdgcn_s_setprio(1);
        #pragma unroll
        for (int ks = 0; ks < 2; ++ks)
            #pragma unroll
            for (int mi = 0; mi < 4; ++mi)
                #pragma unroll
                for (int ni = 0; ni < 4; ++ni)
                    acc[mi][ni] = __builtin_amdgcn_mfma_f32_16x16x32_f16(
                        af[mi][ks], bf[ni][ks], acc[mi][ni], 0, 0, 0);
        __builtin_amdgcn_s_setprio(0);
    }

    const int colBase = n0 + wc * 64;
    const int rowBase = m0 + wr * 64;

    if (MODE == 0) {
        #pragma unroll
        for (int ni = 0; ni < 4; ++ni) {
            int col = colBase + ni * 16 + (lane & 15);
            float bv = bias[col];
            #pragma unroll
            for (int mi = 0; mi < 4; ++mi) {
                int row = rowBase + mi * 16 + g * 4;
                #pragma unroll
                for (int reg = 0; reg < 4; ++reg)
                    C[(size_t)(row + reg) * N + col] = acc[mi][ni][reg] + bv;
            }
        }
    } else {
        #pragma unroll
        for (int ni = 0; ni < 4; ++ni) {
            int col = colBase + ni * 16 + (lane & 15);
            float bv = bias[col];
            int seg = col >> 10;
            int cc = col & 1023;
            int h = cc >> 6, d = cc & 63;
            #pragma unroll
            for (int mi = 0; mi < 4; ++mi) {
                int row = rowBase + mi * 16 + g * 4;
                int b = row >> 11, s = row & 2047;
                size_t bh = (size_t)(b * NH + h);
                if (seg < 2) {
                    unsigned short* dst = (seg ? kb : qb)
                        + bh * 2048 * 64 + (size_t)s * 64 + d;
                    #pragma unroll
                    for (int reg = 0; reg < 4; ++reg)
                        dst[(size_t)reg * 64] = f2h(acc[mi][ni][reg] + bv);
                } else {
                    unsigned short* dst = vtb
                        + bh * 64 * 2048 + (size_t)d * 2048 + s;
                    us4 w;
                    #pragma unroll
                    for (int reg = 0; reg < 4; ++reg)
                        w[reg] = f2h(acc[mi][ni][reg] + bv);
                    *reinterpret_cast<us4*>(dst) = w;
                }
            }
        }
    }
}

// ---------------------------------------------------------------------------
// One (16q x 64k) attention tile for one wave: QK^T, online softmax, PV.
// ---------------------------------------------------------------------------
__device__ __forceinline__ void attn_tile(
    f16x8 qf0, f16x8 qf1,
    const unsigned short* Ks, const unsigned short* Vs, unsigned short* Pw,
    f32x4 (&o)[4], float (&m_)[4], float (&l_)[4],
    int qt, int kt, int qrow_base, int lane, int g) {

    f32x4 s[4];
    #pragma unroll
    for (int n = 0; n < 4; ++n) { s[n][0] = 0.f; s[n][1] = 0.f; s[n][2] = 0.f; s[n][3] = 0.f; }

    __builtin_amdgcn_s_setprio(1);
    #pragma unroll
    for (int ks = 0; ks < 2; ++ks) {
        f16x8 a = ks ? qf1 : qf0;
        #pragma unroll
        for (int n = 0; n < 4; ++n)
            s[n] = __builtin_amdgcn_mfma_f32_16x16x32_f16(
                a, frag16(Ks, n * 16, ks), s[n], 0, 0, 0);
    }
    __builtin_amdgcn_s_setprio(0);

    const int kc0 = kt * 64 + (lane & 15);
    const int qr0 = qrow_base + (g << 2);
    const bool diag = (kt == qt);

    #pragma unroll
    for (int reg = 0; reg < 4; ++reg) {
        float x[4];
        #pragma unroll
        for (int n = 0; n < 4; ++n) {
            x[n] = s[n][reg] * 0.125f;
            if (diag && (kc0 + 16 * n > qr0 + reg)) x[n] = -10000.0f;
        }
        float rmax = fmaxf(fmaxf(x[0], x[1]), fmaxf(x[2], x[3]));
        rmax = fmaxf(rmax, __shfl_xor(rmax, 1));
        rmax = fmaxf(rmax, __shfl_xor(rmax, 2));
        rmax = fmaxf(rmax, __shfl_xor(rmax, 4));
        rmax = fmaxf(rmax, __shfl_xor(rmax, 8));
        float mn = fmaxf(m_[reg], rmax);
        float al = __expf(m_[reg] - mn);
        float ps = 0.f;
        const int prow = (g << 2) + reg;
        #pragma unroll
        for (int n = 0; n < 4; ++n) {
            float p = __expf(x[n] - mn);
            ps += p;
            int pcb = (((lane & 15) + (n << 4)) << 1) ^ ((prow & 7) << 4);
            *reinterpret_cast<unsigned short*>(
                reinterpret_cast<char*>(Pw) + prow * 128 + pcb) = f2h(p);
        }
        ps += __shfl_xor(ps, 1);
        ps += __shfl_xor(ps, 2);
        ps += __shfl_xor(ps, 4);
        ps += __shfl_xor(ps, 8);
        l_[reg] = l_[reg] * al + ps;
        m_[reg] = mn;
        #pragma unroll
        for (int n = 0; n < 4; ++n) o[n][reg] *= al;
    }

    __builtin_amdgcn_s_setprio(1);
    #pragma unroll
    for (int ks = 0; ks < 2; ++ks) {
        f16x8 pa = frag16(Pw, 0, ks);
        #pragma unroll
        for (int n = 0; n < 4; ++n)
            o[n] = __builtin_amdgcn_mfma_f32_16x16x32_f16(
                pa, frag16(Vs, n * 16, ks), o[n], 0, 0, 0);
    }
    __builtin_amdgcn_s_setprio(0);
}

// ---------------------------------------------------------------------------
// MFMA flash attention, diagonal-paired q-tiles {pair, 31-pair}, XCD-aware
// block remap (8 bh per XCD, all 16 pair-blocks of a bh on one XCD -> K/V
// stays in that XCD's L2), async-split K/V staging (issue early, write late).
// ---------------------------------------------------------------------------
__global__ __launch_bounds__(256, 4)
void attn_mfma(const unsigned short* __restrict__ qb,
               const unsigned short* __restrict__ kb,
               const unsigned short* __restrict__ vtb,
               unsigned short* __restrict__ attno) {
    // XCD-aware decode: f&7 = XCD slot; 8 bh per XCD; 16 pairs per bh.
    const int f = blockIdx.x;           // 0..1023
    const int xcd = f & 7;
    const int wi = f >> 3;              // 0..127
    const int bh = xcd * 8 + (wi >> 4); // all 16 pair-blocks of bh -> same XCD
    const int pair = wi & 15;
    const int qtA = pair, qtB = 31 - pair;
    const int tid = threadIdx.x;
    const int wid = tid >> 6, lane = tid & 63, g = lane >> 4;

    __shared__ __align__(16) unsigned short Ks[64 * 64];
    __shared__ __align__(16) unsigned short Vs[64 * 64];
    __shared__ __align__(16) unsigned short Ps[4][16 * 64];

    const unsigned short* kg0 = kb + (size_t)bh * 2048 * 64;
    const unsigned short* vg0 = vtb + (size_t)bh * 64 * 2048;

    // Q fragments direct from global
    const int qrl = wid * 16 + (lane & 15);
    const int qd0 = (lane >> 4) * 8;
    const unsigned short* qbase = qb + (size_t)bh * 2048 * 64;
    f16x8 qA0 = *reinterpret_cast<const f16x8*>(qbase + (size_t)(qtA * 64 + qrl) * 64 + qd0);
    f16x8 qA1 = *reinterpret_cast<const f16x8*>(qbase + (size_t)(qtA * 64 + qrl) * 64 + 32 + qd0);
    f16x8 qB0 = *reinterpret_cast<const f16x8*>(qbase + (size_t)(qtB * 64 + qrl) * 64 + qd0);
    f16x8 qB1 = *reinterpret_cast<const f16x8*>(qbase + (size_t)(qtB * 64 + qrl) * 64 + 32 + qd0);

    f32x4 oA[4], oB[4];
    float mA[4], lA[4], mB[4], lB[4];
    #pragma unroll
    for (int n = 0; n < 4; ++n) {
        #pragma unroll
        for (int r = 0; r < 4; ++r) { oA[n][r] = 0.f; oB[n][r] = 0.f; }
    }
    #pragma unroll
    for (int r = 0; r < 4; ++r) { mA[r] = -1e30f; lA[r] = 0.f; mB[r] = -1e30f; lB[r] = 0.f; }

    unsigned short* Pw = Ps[wid];
    const int qrbA = qtA * 64 + wid * 16;
    const int qrbB = qtB * 64 + wid * 16;

    us8 rk[2], rv[2];
    ldKV(rk, rv, kg0, vg0, tid);                    // kt = 0

    for (int kt = 0; kt <= qtB; ++kt) {
        __syncthreads();                            // consumers of prev LDS done
        wrKV(rk, rv, Ks, Vs, tid);
        __syncthreads();                            // LDS ready
        if (kt < qtB)                               // issue next tile early
            ldKV(rk, rv, kg0 + (size_t)(kt + 1) * 64 * 64,
                 vg0 + (size_t)(kt + 1) * 64, tid);

        attn_tile(qB0, qB1, Ks, Vs, Pw, oB, mB, lB, qtB, kt, qrbB, lane, g);
        if (kt <= qtA)
            attn_tile(qA0, qA1, Ks, Vs, Pw, oA, mA, lA, qtA, kt, qrbA, lane, g);
    }

    const int b = bh >> 4, h = bh & 15;
    #pragma unroll
    for (int ph = 0; ph < 2; ++ph) {
        const int qt = ph ? qtB : qtA;
        f32x4* o = ph ? oB : oA;
        float* l_ = ph ? lB : lA;
        unsigned short* ob = attno
            + (size_t)(b * 2048 + qt * 64 + wid * 16) * 1024 + h * 64;
        #pragma unroll
        for (int reg = 0; reg < 4; ++reg) {
            float inv = 1.0f / l_[reg];
            int row = (g << 2) + reg;
            #pragma unroll
            for (int n = 0; n < 4; ++n)
                ob[(size_t)row * 1024 + n * 16 + (lane & 15)] = f2h(o[n][reg] * inv);
        }
    }
}

// ---------------------------------------------------------------------------
extern "C" void kernel_launch(void* const* d_in, const int* in_sizes, int n_in,
                              void* d_out, int out_size, void* d_ws, size_t ws_size,
                              hipStream_t stream) {
    const float* x    = (const float*)d_in[0];
    const float* Wqkv = (const float*)d_in[1];
    const float* bqkv = (const float*)d_in[2];
    const float* Wp   = (const float*)d_in[3];
    const float* bp   = (const float*)d_in[4];
    float* out = (float*)d_out;

    const int B = 4, S = 2048, D = 1024;
    const int M = B * S;                         // 8192
    const size_t HSZ = (size_t)M * D;            // 8 M elems

    unsigned short* xh    = (unsigned short*)d_ws;   // [M,D]      fp16
    unsigned short* wqt   = xh + HSZ;                // [3D,D]     fp16
    unsigned short* wpt   = wqt + (size_t)3 * D * D; // [D,D]      fp16
    unsigned short* qbuf  = wpt + (size_t)D * D;     // [B,H,S,64]
    unsigned short* kbuf  = qbuf + HSZ;
    unsigned short* vtb   = kbuf + HSZ;
    unsigned short* attno = vtb + HSZ;               // [M,D] fp16

    dim3 blk(256);
    cast_f16<<<dim3((int)(HSZ / 1024)), blk, 0, stream>>>(x, xh);
    transpose_cast<<<dim3(3 * D / 64, D / 64), blk, 0, stream>>>(Wqkv, wqt, D, 3 * D);
    transpose_cast<<<dim3(D / 64, D / 64), blk, 0, stream>>>(Wp, wpt, D, D);

    gemm_f16<1><<<dim3(3 * D / 128, M / 128), blk, 0, stream>>>(
        xh, wqt, bqkv, nullptr, qbuf, kbuf, vtb, M, 3 * D, D);
    attn_mfma<<<dim3(1024), blk, 0, stream>>>(qbuf, kbuf, vtb, attno);
    gemm_f16<0><<<dim3(D / 128, M / 128), blk, 0, stream>>>(
        attno, wpt, bp, out, nullptr, nullptr, nullptr, M, D, D);
}

// Round 6
// 259.447 us; speedup vs baseline: 1.3100x; 1.3100x over previous
//
#include <hip/hip_runtime.h>

#define NH 16
#define HD 64

typedef __attribute__((ext_vector_type(8))) _Float16 f16x8;
typedef __attribute__((ext_vector_type(4))) float f32x4;
typedef __attribute__((ext_vector_type(8))) unsigned short us8;
typedef __attribute__((ext_vector_type(4))) unsigned short us4;

__device__ __forceinline__ unsigned short f2h(float f) {
    _Float16 h = (_Float16)f;
    return __builtin_bit_cast(unsigned short, h);
}

// ---------------------------------------------------------------------------
// cast fp32 -> fp16, 4 elems/thread
// ---------------------------------------------------------------------------
__global__ __launch_bounds__(256)
void cast_f16(const float* __restrict__ in, unsigned short* __restrict__ out) {
    size_t i = ((size_t)blockIdx.x * 256 + threadIdx.x) * 4;
    float4 v = *reinterpret_cast<const float4*>(in + i);
    us4 w;
    w[0] = f2h(v.x); w[1] = f2h(v.y); w[2] = f2h(v.z); w[3] = f2h(v.w);
    *reinterpret_cast<us4*>(out + i) = w;
}

// ---------------------------------------------------------------------------
// transpose + cast: in fp32 [R,C] -> out fp16 [C,R].  64x64 tiles.
// ---------------------------------------------------------------------------
__global__ __launch_bounds__(256)
void transpose_cast(const float* __restrict__ in, unsigned short* __restrict__ out,
                    int R, int C) {
    __shared__ float T[64][65];
    const int c0 = blockIdx.x * 64, r0 = blockIdx.y * 64;
    const int tid = threadIdx.x;
    const int rr = tid >> 4, cc4 = (tid & 15) * 4;
    #pragma unroll
    for (int p = 0; p < 4; ++p) {
        int r = rr + p * 16;
        float4 v = *reinterpret_cast<const float4*>(
            in + (size_t)(r0 + r) * C + c0 + cc4);
        T[r][cc4] = v.x; T[r][cc4 + 1] = v.y; T[r][cc4 + 2] = v.z; T[r][cc4 + 3] = v.w;
    }
    __syncthreads();
    #pragma unroll
    for (int p = 0; p < 4; ++p) {
        int orow = rr + p * 16;     // output row = input col
        us4 w;
        #pragma unroll
        for (int j = 0; j < 4; ++j) w[j] = f2h(T[cc4 + j][orow]);
        *reinterpret_cast<us4*>(out + (size_t)(c0 + orow) * R + r0 + cc4) = w;
    }
}

// ---------------------------------------------------------------------------
// LDS staging with XOR swizzle (rows of 128B = 64 fp16).
// lds byte = r*128 + ((slot*16) ^ ((r&7)<<4))
// ---------------------------------------------------------------------------
__device__ __forceinline__ void stage128(unsigned short* dst,
                                         const unsigned short* src, int stride) {
    const int tid = threadIdx.x;
    #pragma unroll
    for (int p = 0; p < 4; ++p) {
        int idx = tid + p * 256;
        int r = idx >> 3;
        int slot = idx & 7;
        us8 v = *reinterpret_cast<const us8*>(src + (size_t)r * stride + slot * 8);
        int cb = (slot << 4) ^ ((r & 7) << 4);
        *reinterpret_cast<us8*>(reinterpret_cast<char*>(dst) + r * 128 + cb) = v;
    }
}

__device__ __forceinline__ void stage64(unsigned short* dst,
                                        const unsigned short* src, int stride) {
    const int tid = threadIdx.x;
    #pragma unroll
    for (int p = 0; p < 2; ++p) {
        int idx = tid + p * 256;
        int r = idx >> 3;
        int slot = idx & 7;
        us8 v = *reinterpret_cast<const us8*>(src + (size_t)r * stride + slot * 8);
        int cb = (slot << 4) ^ ((r & 7) << 4);
        *reinterpret_cast<us8*>(reinterpret_cast<char*>(dst) + r * 128 + cb) = v;
    }
}

// Fragment load: lane l -> row row0+(l&15), bytes [ks*64 + (l>>4)*16, +16) ^ swz
__device__ __forceinline__ f16x8 frag16(const unsigned short* base, int row0, int ks) {
    const int lane = threadIdx.x & 63;
    const int r = row0 + (lane & 15);
    int cb = ((ks << 6) + (lane & 48)) ^ ((r & 7) << 4);
    return *reinterpret_cast<const f16x8*>(
        reinterpret_cast<const char*>(base) + r * 128 + cb);
}

// ---------------------------------------------------------------------------
// MFMA GEMM core: C[M,N] = A[M,K] @ Bt[N,K]^T.  128x128 tile, BK=64, 4 waves.
// MODE 0: proj  (fp32 C + bias)
// MODE 1: qkv   (split into q,k [B,H,S,64] fp16 and v^T [B,H,64,S] fp16)
// ---------------------------------------------------------------------------
template<int MODE>
__global__ __launch_bounds__(256)
void gemm_f16(const unsigned short* __restrict__ A,
              const unsigned short* __restrict__ Bt,
              const float* __restrict__ bias,
              float* __restrict__ C,
              unsigned short* __restrict__ qb,
              unsigned short* __restrict__ kb,
              unsigned short* __restrict__ vtb,
              int M, int N, int K) {
    __shared__ __align__(16) unsigned short As[128 * 64];
    __shared__ __align__(16) unsigned short Bs[128 * 64];

    const int tid = threadIdx.x;
    const int wid = tid >> 6, lane = tid & 63, g = lane >> 4;
    const int wr = wid >> 1, wc = wid & 1;
    const int m0 = blockIdx.y * 128, n0 = blockIdx.x * 128;

    f32x4 acc[4][4];
    #pragma unroll
    for (int i = 0; i < 4; ++i)
        #pragma unroll
        for (int j = 0; j < 4; ++j) {
            acc[i][j][0] = 0.f; acc[i][j][1] = 0.f;
            acc[i][j][2] = 0.f; acc[i][j][3] = 0.f;
        }

    for (int k0 = 0; k0 < K; k0 += 64) {
        __syncthreads();
        stage128(As, A + (size_t)m0 * K + k0, K);
        stage128(Bs, Bt + (size_t)n0 * K + k0, K);
        __syncthreads();

        f16x8 af[4][2], bf[4][2];
        #pragma unroll
        for (int mi = 0; mi < 4; ++mi)
            #pragma unroll
            for (int ks = 0; ks < 2; ++ks)
                af[mi][ks] = frag16(As, wr * 64 + mi * 16, ks);
        #pragma unroll
        for (int ni = 0; ni < 4; ++ni)
            #pragma unroll
            for (int ks = 0; ks < 2; ++ks)
                bf[ni][ks] = frag16(Bs, wc * 64 + ni * 16, ks);

        __builtin_amdgcn_s_setprio(1);
        #pragma unroll
        for (int ks = 0; ks < 2; ++ks)
            #pragma unroll
            for (int mi = 0; mi < 4; ++mi)
                #pragma unroll
                for (int ni = 0; ni < 4; ++ni)
                    acc[mi][ni] = __builtin_amdgcn_mfma_f32_16x16x32_f16(
                        af[mi][ks], bf[ni][ks], acc[mi][ni], 0, 0, 0);
        __builtin_amdgcn_s_setprio(0);
    }

    const int colBase = n0 + wc * 64;
    const int rowBase = m0 + wr * 64;

    if (MODE == 0) {
        #pragma unroll
        for (int ni = 0; ni < 4; ++ni) {
            int col = colBase + ni * 16 + (lane & 15);
            float bv = bias[col];
            #pragma unroll
            for (int mi = 0; mi < 4; ++mi) {
                int row = rowBase + mi * 16 + g * 4;
                #pragma unroll
                for (int reg = 0; reg < 4; ++reg)
                    C[(size_t)(row + reg) * N + col] = acc[mi][ni][reg] + bv;
            }
        }
    } else {
        #pragma unroll
        for (int ni = 0; ni < 4; ++ni) {
            int col = colBase + ni * 16 + (lane & 15);
            float bv = bias[col];
            int seg = col >> 10;
            int cc = col & 1023;
            int h = cc >> 6, d = cc & 63;
            #pragma unroll
            for (int mi = 0; mi < 4; ++mi) {
                int row = rowBase + mi * 16 + g * 4;
                int b = row >> 11, s = row & 2047;
                size_t bh = (size_t)(b * NH + h);
                if (seg < 2) {
                    unsigned short* dst = (seg ? kb : qb)
                        + bh * 2048 * 64 + (size_t)s * 64 + d;
                    #pragma unroll
                    for (int reg = 0; reg < 4; ++reg)
                        dst[(size_t)reg * 64] = f2h(acc[mi][ni][reg] + bv);
                } else {
                    unsigned short* dst = vtb
                        + bh * 64 * 2048 + (size_t)d * 2048 + s;
                    us4 w;
                    #pragma unroll
                    for (int reg = 0; reg < 4; ++reg)
                        w[reg] = f2h(acc[mi][ni][reg] + bv);
                    *reinterpret_cast<us4*>(dst) = w;
                }
            }
        }
    }
}

// ---------------------------------------------------------------------------
// One (16q x 64k) attention tile for one wave: QK^T, online softmax, PV.
// ---------------------------------------------------------------------------
__device__ __forceinline__ void attn_tile(
    f16x8 qf0, f16x8 qf1,
    const unsigned short* Ks, const unsigned short* Vs, unsigned short* Pw,
    f32x4 (&o)[4], float (&m_)[4], float (&l_)[4],
    int qt, int kt, int qrow_base, int lane, int g) {

    f32x4 s[4];
    #pragma unroll
    for (int n = 0; n < 4; ++n) { s[n][0] = 0.f; s[n][1] = 0.f; s[n][2] = 0.f; s[n][3] = 0.f; }

    __builtin_amdgcn_s_setprio(1);
    #pragma unroll
    for (int ks = 0; ks < 2; ++ks) {
        f16x8 a = ks ? qf1 : qf0;
        #pragma unroll
        for (int n = 0; n < 4; ++n)
            s[n] = __builtin_amdgcn_mfma_f32_16x16x32_f16(
                a, frag16(Ks, n * 16, ks), s[n], 0, 0, 0);
    }
    __builtin_amdgcn_s_setprio(0);

    const int kc0 = kt * 64 + (lane & 15);
    const int qr0 = qrow_base + (g << 2);
    const bool diag = (kt == qt);

    #pragma unroll
    for (int reg = 0; reg < 4; ++reg) {
        float x[4];
        #pragma unroll
        for (int n = 0; n < 4; ++n) {
            x[n] = s[n][reg] * 0.125f;
            if (diag && (kc0 + 16 * n > qr0 + reg)) x[n] = -10000.0f;
        }
        float rmax = fmaxf(fmaxf(x[0], x[1]), fmaxf(x[2], x[3]));
        rmax = fmaxf(rmax, __shfl_xor(rmax, 1));
        rmax = fmaxf(rmax, __shfl_xor(rmax, 2));
        rmax = fmaxf(rmax, __shfl_xor(rmax, 4));
        rmax = fmaxf(rmax, __shfl_xor(rmax, 8));
        float mn = fmaxf(m_[reg], rmax);
        float al = __expf(m_[reg] - mn);
        float ps = 0.f;
        const int prow = (g << 2) + reg;
        #pragma unroll
        for (int n = 0; n < 4; ++n) {
            float p = __expf(x[n] - mn);
            ps += p;
            int pcb = (((lane & 15) + (n << 4)) << 1) ^ ((prow & 7) << 4);
            *reinterpret_cast<unsigned short*>(
                reinterpret_cast<char*>(Pw) + prow * 128 + pcb) = f2h(p);
        }
        ps += __shfl_xor(ps, 1);
        ps += __shfl_xor(ps, 2);
        ps += __shfl_xor(ps, 4);
        ps += __shfl_xor(ps, 8);
        l_[reg] = l_[reg] * al + ps;
        m_[reg] = mn;
        #pragma unroll
        for (int n = 0; n < 4; ++n) o[n][reg] *= al;
    }

    __builtin_amdgcn_s_setprio(1);
    #pragma unroll
    for (int ks = 0; ks < 2; ++ks) {
        f16x8 pa = frag16(Pw, 0, ks);
        #pragma unroll
        for (int n = 0; n < 4; ++n)
            o[n] = __builtin_amdgcn_mfma_f32_16x16x32_f16(
                pa, frag16(Vs, n * 16, ks), o[n], 0, 0, 0);
    }
    __builtin_amdgcn_s_setprio(0);
}

// ---------------------------------------------------------------------------
// MFMA flash attention, diagonal-paired q-tiles {pair, 31-pair}.
// XCD-aware block remap (8 bh per XCD, all 16 pair-blocks of a bh on one
// XCD so K/V stays in that XCD's L2).  Direct LDS staging (round-4 proven;
// round-5's reg-split spilled to scratch and thrashed L2 -> reverted).
// ---------------------------------------------------------------------------
__global__ __launch_bounds__(256, 4)
void attn_mfma(const unsigned short* __restrict__ qb,
               const unsigned short* __restrict__ kb,
               const unsigned short* __restrict__ vtb,
               unsigned short* __restrict__ attno) {
    // XCD-aware decode: f&7 = XCD slot; 8 bh per XCD; 16 pairs per bh.
    const int f = blockIdx.x;           // 0..1023
    const int xcd = f & 7;
    const int wi = f >> 3;              // 0..127
    const int bh = xcd * 8 + (wi >> 4); // all 16 pair-blocks of bh -> same XCD
    const int pair = wi & 15;
    const int qtA = pair, qtB = 31 - pair;
    const int tid = threadIdx.x;
    const int wid = tid >> 6, lane = tid & 63, g = lane >> 4;

    __shared__ __align__(16) unsigned short Ks[64 * 64];
    __shared__ __align__(16) unsigned short Vs[64 * 64];
    __shared__ __align__(16) unsigned short Ps[4][16 * 64];

    const unsigned short* kg0 = kb + (size_t)bh * 2048 * 64;
    const unsigned short* vg0 = vtb + (size_t)bh * 64 * 2048;

    // Q fragments direct from global
    const int qrl = wid * 16 + (lane & 15);
    const int qd0 = (lane >> 4) * 8;
    const unsigned short* qbase = qb + (size_t)bh * 2048 * 64;
    f16x8 qA0 = *reinterpret_cast<const f16x8*>(qbase + (size_t)(qtA * 64 + qrl) * 64 + qd0);
    f16x8 qA1 = *reinterpret_cast<const f16x8*>(qbase + (size_t)(qtA * 64 + qrl) * 64 + 32 + qd0);
    f16x8 qB0 = *reinterpret_cast<const f16x8*>(qbase + (size_t)(qtB * 64 + qrl) * 64 + qd0);
    f16x8 qB1 = *reinterpret_cast<const f16x8*>(qbase + (size_t)(qtB * 64 + qrl) * 64 + 32 + qd0);

    f32x4 oA[4], oB[4];
    float mA[4], lA[4], mB[4], lB[4];
    #pragma unroll
    for (int n = 0; n < 4; ++n) {
        #pragma unroll
        for (int r = 0; r < 4; ++r) { oA[n][r] = 0.f; oB[n][r] = 0.f; }
    }
    #pragma unroll
    for (int r = 0; r < 4; ++r) { mA[r] = -1e30f; lA[r] = 0.f; mB[r] = -1e30f; lB[r] = 0.f; }

    unsigned short* Pw = Ps[wid];
    const int qrbA = qtA * 64 + wid * 16;
    const int qrbB = qtB * 64 + wid * 16;

    for (int kt = 0; kt <= qtB; ++kt) {
        __syncthreads();
        stage64(Ks, kg0 + (size_t)kt * 64 * 64, 64);
        stage64(Vs, vg0 + (size_t)kt * 64, 2048);
        __syncthreads();

        attn_tile(qB0, qB1, Ks, Vs, Pw, oB, mB, lB, qtB, kt, qrbB, lane, g);
        if (kt <= qtA)
            attn_tile(qA0, qA1, Ks, Vs, Pw, oA, mA, lA, qtA, kt, qrbA, lane, g);
    }

    const int b = bh >> 4, h = bh & 15;
    #pragma unroll
    for (int ph = 0; ph < 2; ++ph) {
        const int qt = ph ? qtB : qtA;
        f32x4* o = ph ? oB : oA;
        float* l_ = ph ? lB : lA;
        unsigned short* ob = attno
            + (size_t)(b * 2048 + qt * 64 + wid * 16) * 1024 + h * 64;
        #pragma unroll
        for (int reg = 0; reg < 4; ++reg) {
            float inv = 1.0f / l_[reg];
            int row = (g << 2) + reg;
            #pragma unroll
            for (int n = 0; n < 4; ++n)
                ob[(size_t)row * 1024 + n * 16 + (lane & 15)] = f2h(o[n][reg] * inv);
        }
    }
}

// ---------------------------------------------------------------------------
extern "C" void kernel_launch(void* const* d_in, const int* in_sizes, int n_in,
                              void* d_out, int out_size, void* d_ws, size_t ws_size,
                              hipStream_t stream) {
    const float* x    = (const float*)d_in[0];
    const float* Wqkv = (const float*)d_in[1];
    const float* bqkv = (const float*)d_in[2];
    const float* Wp   = (const float*)d_in[3];
    const float* bp   = (const float*)d_in[4];
    float* out = (float*)d_out;

    const int B = 4, S = 2048, D = 1024;
    const int M = B * S;                         // 8192
    const size_t HSZ = (size_t)M * D;            // 8 M elems

    unsigned short* xh    = (unsigned short*)d_ws;   // [M,D]      fp16
    unsigned short* wqt   = xh + HSZ;                // [3D,D]     fp16
    unsigned short* wpt   = wqt + (size_t)3 * D * D; // [D,D]      fp16
    unsigned short* qbuf  = wpt + (size_t)D * D;     // [B,H,S,64]
    unsigned short* kbuf  = qbuf + HSZ;
    unsigned short* vtb   = kbuf + HSZ;
    unsigned short* attno = vtb + HSZ;               // [M,D] fp16

    dim3 blk(256);
    cast_f16<<<dim3((int)(HSZ / 1024)), blk, 0, stream>>>(x, xh);
    transpose_cast<<<dim3(3 * D / 64, D / 64), blk, 0, stream>>>(Wqkv, wqt, D, 3 * D);
    transpose_cast<<<dim3(D / 64, D / 64), blk, 0, stream>>>(Wp, wpt, D, D);

    gemm_f16<1><<<dim3(3 * D / 128, M / 128), blk, 0, stream>>>(
        xh, wqt, bqkv, nullptr, qbuf, kbuf, vtb, M, 3 * D, D);
    attn_mfma<<<dim3(1024), blk, 0, stream>>>(qbuf, kbuf, vtb, attno);
    gemm_f16<0><<<dim3(D / 128, M / 128), blk, 0, stream>>>(
        attno, wpt, bp, out, nullptr, nullptr, nullptr, M, D, D);
}